// Round 5
// baseline (319.129 us; speedup 1.0000x reference)
//
#include <hip/hip_runtime.h>
#include <stdint.h>

typedef __bf16 bf16x8 __attribute__((ext_vector_type(8)));
typedef float f32x4 __attribute__((ext_vector_type(4)));

__device__ __forceinline__ unsigned int f2bf(float f) {
  unsigned int u = __float_as_uint(f);
  return (u + 0x7fffu + ((u >> 16) & 1u)) >> 16;  // RNE
}
__device__ __forceinline__ unsigned int pack2(float a, float b) {
  return f2bf(a) | (f2bf(b) << 16);
}
__device__ __forceinline__ float bf2f(unsigned int u) {
  return __uint_as_float(u << 16);
}

__device__ __forceinline__ void fwht16(float v[16]) {
#pragma unroll
  for (int s = 0; s < 4; ++s) {
    const int h = 1 << s;
#pragma unroll
    for (int i = 0; i < 16; ++i) {
      if (!(i & h)) {
        float a = v[i], b = v[i ^ h];
        v[i] = a + b;
        v[i ^ h] = a - b;
      }
    }
  }
}

#define LP(i) ((i) + ((i) >> 5))  // padded LDS index

// ---------------------------------------------------------------------------
// K0: Xbf = bf16(x)  — pure stream
// ---------------------------------------------------------------------------
__global__ void __launch_bounds__(256) k_cast(const float* __restrict__ X,
                                              unsigned short* __restrict__ Xb) {
  size_t i = (size_t)blockIdx.x * 2048 + (size_t)threadIdx.x * 8;
  float4 a = *(const float4*)(X + i);
  float4 b = *(const float4*)(X + i + 4);
  uint4 o;
  o.x = pack2(a.x, a.y);
  o.y = pack2(a.z, a.w);
  o.z = pack2(b.x, b.y);
  o.w = pack2(b.z, b.w);
  *(uint4*)(Xb + i) = o;
}

// ---------------------------------------------------------------------------
// K1: per W-row m: decompress -> FWHT_k(4096)*(1/64) -> *SU -> bf16
// radix-16 register FWHT; extra final LDS exchange so stores are uint4.
// ---------------------------------------------------------------------------
__global__ void __launch_bounds__(256) k_wrow(const int* __restrict__ Qidxs,
                                              const float* __restrict__ G,
                                              const float* __restrict__ SU,
                                              unsigned short* __restrict__ W) {
  __shared__ float lds[4224];
  const int t = threadIdx.x;
  const size_t m = blockIdx.x;
  int2 code = ((const int2*)(Qidxs + m * 512))[t];
  const float4* g0 = (const float4*)(G + (size_t)code.x * 8);
  const float4* g1 = (const float4*)(G + (size_t)code.y * 8);
  float4 c0 = g0[0], c1 = g0[1], c2 = g1[0], c3 = g1[1];
  float v[16] = {c0.x, c0.y, c0.z, c0.w, c1.x, c1.y, c1.z, c1.w,
                 c2.x, c2.y, c2.z, c2.w, c3.x, c3.y, c3.z, c3.w};
  fwht16(v);  // bits 0-3
#pragma unroll
  for (int q = 0; q < 4; ++q) {
    int i0 = 16 * t + 4 * q;
    *(float4*)&lds[LP(i0)] = make_float4(v[4 * q], v[4 * q + 1], v[4 * q + 2], v[4 * q + 3]);
  }
  __syncthreads();
  const int b = ((t >> 4) << 8) | (t & 15);
#pragma unroll
  for (int j = 0; j < 16; ++j) { int i = b + 16 * j; v[j] = lds[LP(i)]; }
  fwht16(v);  // bits 4-7
#pragma unroll
  for (int j = 0; j < 16; ++j) { int i = b + 16 * j; lds[LP(i)] = v[j]; }
  __syncthreads();
#pragma unroll
  for (int j = 0; j < 16; ++j) { int i = t + 256 * j; v[j] = lds[LP(i)]; }
  fwht16(v);  // bits 8-11
  __syncthreads();  // lds reuse
#pragma unroll
  for (int j = 0; j < 16; ++j) { int i = t + 256 * j; lds[LP(i)] = v[j]; }
  __syncthreads();
  // now read contiguous 16t..16t+15, fold SU * 1/64, pack, 2x uint4 stores
  unsigned short* orow = W + m * 4096;
  const float4* su = (const float4*)SU;
  uint4 o0, o1;
  {
    float4 a = *(const float4*)&lds[LP(16 * t + 0)], s = su[4 * t + 0];
    float4 bq = *(const float4*)&lds[LP(16 * t + 4)], s1 = su[4 * t + 1];
    o0.x = pack2(a.x * s.x * 0.015625f, a.y * s.y * 0.015625f);
    o0.y = pack2(a.z * s.z * 0.015625f, a.w * s.w * 0.015625f);
    o0.z = pack2(bq.x * s1.x * 0.015625f, bq.y * s1.y * 0.015625f);
    o0.w = pack2(bq.z * s1.z * 0.015625f, bq.w * s1.w * 0.015625f);
  }
  {
    float4 a = *(const float4*)&lds[LP(16 * t + 8)], s = su[4 * t + 2];
    float4 bq = *(const float4*)&lds[LP(16 * t + 12)], s1 = su[4 * t + 3];
    o1.x = pack2(a.x * s.x * 0.015625f, a.y * s.y * 0.015625f);
    o1.y = pack2(a.z * s.z * 0.015625f, a.w * s.w * 0.015625f);
    o1.z = pack2(bq.x * s1.x * 0.015625f, bq.y * s1.y * 0.015625f);
    o1.w = pack2(bq.z * s1.z * 0.015625f, bq.w * s1.w * 0.015625f);
  }
  ((uint4*)(orow + 16 * t))[0] = o0;
  ((uint4*)(orow + 16 * t))[1] = o1;
}

// ---------------------------------------------------------------------------
// K2: H64 (unnormalized) over the m index, in place, LDS-tiled.
// Block = one 64-row H64 chain group x 256 columns; all global I/O uint4.
// m = blockIdx.y * rowbase_mult + r * rowstride, r = 0..63.
//   pass1 (low 6 bits):  rowbase_mult=64, rowstride=1
//   pass2 (high 6 bits): rowbase_mult=1,  rowstride=64
// 1/64 normalization folded into GEMM epilogue.
// ---------------------------------------------------------------------------
__global__ void __launch_bounds__(256) k_wm(unsigned short* __restrict__ W,
                                            int rowbase_mult, int rowstride) {
  __shared__ unsigned short tile[64][256];  // 32 KB; col reads are 2-way (free)
  const int t = threadIdx.x;
  const int c0 = blockIdx.x * 256;
  const int rowbase = blockIdx.y * rowbase_mult;
  // load: 2048 16B-chunks, 8 per thread; 32 chunks per row
#pragma unroll
  for (int it = 0; it < 8; ++it) {
    int ch = it * 256 + t;
    int r = ch >> 5;
    int off = (ch & 31) * 8;
    size_t g = (size_t)(rowbase + r * rowstride) * 4096 + c0 + off;
    *(uint4*)&tile[r][off] = *(const uint4*)&W[g];
  }
  __syncthreads();
  float v[64];
#pragma unroll
  for (int r = 0; r < 64; ++r) v[r] = bf2f(tile[r][t]);
#pragma unroll
  for (int s = 0; s < 6; ++s) {
    const int h = 1 << s;
#pragma unroll
    for (int i = 0; i < 64; ++i) {
      if (!(i & h)) {
        float a = v[i], bb = v[i ^ h];
        v[i] = a + bb;
        v[i ^ h] = a - bb;
      }
    }
  }
#pragma unroll
  for (int r = 0; r < 64; ++r) tile[r][t] = (unsigned short)f2bf(v[r]);
  __syncthreads();
#pragma unroll
  for (int it = 0; it < 8; ++it) {
    int ch = it * 256 + t;
    int r = ch >> 5;
    int off = (ch & 31) * 8;
    size_t g = (size_t)(rowbase + r * rowstride) * 4096 + c0 + off;
    *(uint4*)&W[g] = *(const uint4*)&tile[r][off];
  }
}

// ---------------------------------------------------------------------------
// K3: GEMM C = A @ B^T (bf16 [4096][4096], K-major), fp32 out, *SV*(1/64).
// m97 recipe + XOR swizzle on the GLOBAL address (R2: conflicts 5e7 -> 0).
// ---------------------------------------------------------------------------
__device__ __forceinline__ void gl2lds16(const unsigned short* g, unsigned short* l) {
  __builtin_amdgcn_global_load_lds(
      (const __attribute__((address_space(1))) void*)g,
      (__attribute__((address_space(3))) void*)l, 16, 0, 0);
}

__global__ void __launch_bounds__(256) k_gemm_bt(const unsigned short* __restrict__ A,
                                                 const unsigned short* __restrict__ B,
                                                 const float* __restrict__ SV,
                                                 float* __restrict__ C) {
  const int K = 4096, N = 4096;
  __shared__ unsigned short sA[128 * 64];
  __shared__ unsigned short sB[128 * 64];
  const int tid = threadIdx.x;
  const int wave = tid >> 6, lane = tid & 63;
  const int bn = blockIdx.x, bm = blockIdx.y;
  const int wr = wave >> 1, wc = wave & 1;
  const int frow = lane & 15;
  const int sw = frow & 7;
  const int jbase = lane >> 4;
  f32x4 acc[4][4] = {};

  const size_t rowA0 = (size_t)bm * 128;
  const size_t rowB0 = (size_t)bn * 128;

  for (int kt = 0; kt < K; kt += 64) {
    __syncthreads();
#pragma unroll
    for (int it = 0; it < 4; ++it) {
      int c = it * 256 + tid;
      int r = c >> 3;
      int jg = (c & 7) ^ (r & 7);
      int kc = jg * 8;
      unsigned short* la = &sA[(it * 256 + wave * 64) * 8];
      unsigned short* lb = &sB[(it * 256 + wave * 64) * 8];
      gl2lds16(A + (rowA0 + r) * K + kt + kc, la);
      gl2lds16(B + (rowB0 + r) * K + kt + kc, lb);
    }
    __syncthreads();
#pragma unroll
    for (int kk = 0; kk < 64; kk += 32) {
      bf16x8 af[4], bfr[4];
      int jn = (kk >> 3) + jbase;
      int js = jn ^ sw;
#pragma unroll
      for (int i = 0; i < 4; ++i)
        af[i] = *(const bf16x8*)&sA[(wr * 64 + i * 16 + frow) * 64 + js * 8];
#pragma unroll
      for (int j = 0; j < 4; ++j)
        bfr[j] = *(const bf16x8*)&sB[(wc * 64 + j * 16 + frow) * 64 + js * 8];
#pragma unroll
      for (int i = 0; i < 4; ++i)
#pragma unroll
        for (int j = 0; j < 4; ++j)
          acc[i][j] = __builtin_amdgcn_mfma_f32_16x16x32_bf16(af[i], bfr[j], acc[i][j], 0, 0, 0);
    }
  }
  const int crow = bm * 128 + wr * 64 + (lane >> 4) * 4;
  const int ccol = bn * 128 + wc * 64 + (lane & 15);
  float sv[4];
#pragma unroll
  for (int j = 0; j < 4; ++j) sv[j] = SV[ccol + 16 * j] * 0.015625f;
#pragma unroll
  for (int i = 0; i < 4; ++i)
#pragma unroll
    for (int j = 0; j < 4; ++j) {
      float* cp = C + (size_t)(crow + i * 16) * N + ccol + j * 16;
#pragma unroll
      for (int r = 0; r < 4; ++r) cp[(size_t)r * N] = acc[i][j][r] * sv[j];
    }
}

// ---------------------------------------------------------------------------
extern "C" void kernel_launch(void* const* d_in, const int* in_sizes, int n_in,
                              void* d_out, int out_size, void* d_ws, size_t ws_size,
                              hipStream_t stream) {
  const float* X     = (const float*)d_in[0];
  const float* SU    = (const float*)d_in[1];
  const float* SV    = (const float*)d_in[2];
  const float* G     = (const float*)d_in[3];
  const int*   Qidxs = (const int*)d_in[4];
  float* out = (float*)d_out;

  unsigned short* Xb = (unsigned short*)d_ws;       // 32 MB
  unsigned short* Wh = Xb + (size_t)4096 * 4096;    // 32 MB

  k_cast<<<8192, 256, 0, stream>>>(X, Xb);
  k_wrow<<<4096, 256, 0, stream>>>(Qidxs, G, SU, Wh);
  k_wm<<<dim3(16, 64), 256, 0, stream>>>(Wh, 64, 1);   // low 6 bits of m
  k_wm<<<dim3(16, 64), 256, 0, stream>>>(Wh, 1, 64);   // high 6 bits of m
  k_gemm_bt<<<dim3(32, 32), 256, 0, stream>>>(Xb, Wh, SV, out);
}